// Round 3
// baseline (981.233 us; speedup 1.0000x reference)
//
#include <hip/hip_runtime.h>

#define CI 4
#define CO 8
#define TT 8
#define S 96
#define SLICE (S*S*S)          // 884736 elements per (c,t) slice
#define NSLICE (CI*TT)         // 32 slices
#define EPS 1e-5f

// ws layout (floats): [0:32) sum, [32:64) sumsq, [64:96) rstd, [96:128) -mean*rstd

__global__ __launch_bounds__(256) void stats_partial(
        const float* __restrict__ x, float* __restrict__ ws) {
    const int slice = blockIdx.y;
    const float4* p = reinterpret_cast<const float4*>(x + (size_t)slice * SLICE);
    const int n4 = SLICE / 4;  // 221184
    float s = 0.f, ss = 0.f;
    for (int i = blockIdx.x * blockDim.x + threadIdx.x; i < n4;
         i += gridDim.x * blockDim.x) {
        float4 v = p[i];
        s  += v.x + v.y + v.z + v.w;
        ss += v.x*v.x + v.y*v.y + v.z*v.z + v.w*v.w;
    }
    #pragma unroll
    for (int off = 32; off > 0; off >>= 1) {
        s  += __shfl_down(s, off);
        ss += __shfl_down(ss, off);
    }
    __shared__ float ls[4], lss[4];
    const int lane = threadIdx.x & 63, wid = threadIdx.x >> 6;
    if (lane == 0) { ls[wid] = s; lss[wid] = ss; }
    __syncthreads();
    if (threadIdx.x == 0) {
        float ts = 0.f, tss = 0.f;
        #pragma unroll
        for (int i = 0; i < 4; i++) { ts += ls[i]; tss += lss[i]; }
        atomicAdd(&ws[slice], ts);
        atomicAdd(&ws[NSLICE + slice], tss);
    }
}

__global__ void stats_final(float* __restrict__ ws) {
    const int i = threadIdx.x;
    if (i < NSLICE) {
        const float inv_n = 1.f / (float)SLICE;
        float mean = ws[i] * inv_n;
        float var  = ws[NSLICE + i] * inv_n - mean * mean;
        float rstd = rsqrtf(var + EPS);
        ws[2*NSLICE + i] = rstd;
        ws[3*NSLICE + i] = -mean * rstd;
    }
}

// One thread per output (t,d,h,w); 8 C_out accumulators.
// Norm+ReLU fused on every input load: relu(fma(x, rstd, -mean*rstd)).
// Conv zero-padding applied AFTER norm/relu via float masks (fwl/fwr) for the
// w edge; t/d/h edges via (near-)uniform scalar-branch `continue`s.
__global__ __launch_bounds__(192) void conv4d_fused(
        const float* __restrict__ x, const float* __restrict__ wgt,
        const float* __restrict__ bias, const float* __restrict__ ws,
        float* __restrict__ out) {
    const int wq = threadIdx.x;                 // 0..95
    const int h  = blockIdx.y * 2 + threadIdx.y;
    const int d  = blockIdx.x;
    const int t  = blockIdx.z;

    float acc[CO];
    #pragma unroll
    for (int co = 0; co < CO; co++) acc[co] = 0.f;

    const bool wl = (wq > 0), wr = (wq < S - 1);
    const int  om1 = wl ? -1 : 0;        // clamped offsets: loads always in-range
    const int  op1 = wr ?  1 : 0;
    const float fwl = wl ? 1.f : 0.f, fwr = wr ? 1.f : 0.f;

    for (int ci = 0; ci < CI; ci++) {
        for (int kt = 0; kt < 3; kt++) {
            const int tt = t + kt - 1;
            if ((unsigned)tt >= TT) continue;
            const int sl = ci * TT + tt;
            const float rstd = ws[2*NSLICE + sl];
            const float nmr  = ws[3*NSLICE + sl];
            const float* xs = x + (size_t)sl * SLICE;
            for (int kd = 0; kd < 3; kd++) {
                const int dd = d + kd - 1;
                if ((unsigned)dd >= S) continue;
                for (int kh = 0; kh < 3; kh++) {
                    const int hh = h + kh - 1;
                    if ((unsigned)hh >= S) continue;
                    const float* row = xs + ((size_t)dd * S + hh) * S + wq;
                    float v0 = fwl * fmaxf(fmaf(row[om1], rstd, nmr), 0.f);
                    float v1 =       fmaxf(fmaf(row[0],   rstd, nmr), 0.f);
                    float v2 = fwr * fmaxf(fmaf(row[op1], rstd, nmr), 0.f);
                    // weight flat idx: co*324 + ci*81 + kt*27 + kd*9 + kh*3 + kw
                    const float* wp = wgt + (((ci * 3 + kt) * 3 + kd) * 3 + kh) * 3;
                    #pragma unroll
                    for (int co = 0; co < CO; co++) {
                        const float* wc = wp + co * (CI * 81);  // uniform -> s_load
                        acc[co] = fmaf(v0, wc[0], acc[co]);
                        acc[co] = fmaf(v1, wc[1], acc[co]);
                        acc[co] = fmaf(v2, wc[2], acc[co]);
                    }
                }
            }
        }
    }
    // out shape (1, CO, T, D, H, W)
    const size_t obase = (((size_t)t * S + d) * S + h) * S + wq;
    #pragma unroll
    for (int co = 0; co < CO; co++) {
        out[(size_t)co * ((size_t)TT * SLICE) + obase] = acc[co] + bias[co];
    }
}

extern "C" void kernel_launch(void* const* d_in, const int* in_sizes, int n_in,
                              void* d_out, int out_size, void* d_ws, size_t ws_size,
                              hipStream_t stream) {
    const float* x   = (const float*)d_in[0];
    const float* w   = (const float*)d_in[1];
    const float* b   = (const float*)d_in[2];
    float* out = (float*)d_out;
    float* ws  = (float*)d_ws;

    // zero the atomic accumulators (ws is poisoned 0xAA before every launch)
    hipMemsetAsync(ws, 0, 2 * NSLICE * sizeof(float), stream);
    stats_partial<<<dim3(32, NSLICE), 256, 0, stream>>>(x, ws);
    stats_final<<<1, 64, 0, stream>>>(ws);
    conv4d_fused<<<dim3(S, S/2, TT), dim3(S, 2, 1), 0, stream>>>(x, w, b, ws, out);
}